// Round 6
// baseline (125.831 us; speedup 1.0000x reference)
//
#include <hip/hip_runtime.h>
#include <hip/hip_bf16.h>

#define N_NODES 8192
#define DIM 128
#define MASK_THRESH 0.8f
#define RB 64             // row-blocks: 8192 / 128 rows
#define KSTEP 64          // k elements staged per step

using f32x4  = __attribute__((ext_vector_type(4))) float;
using bf16x8 = __attribute__((ext_vector_type(8))) short;

static __device__ __forceinline__ short f2bf(float f) {
    unsigned u = __builtin_bit_cast(unsigned, f);
    u += 0x7fffu + ((u >> 16) & 1u);
    return (short)(u >> 16);
}

// async global->LDS, 16B/lane; LDS dest = wave-uniform base (+lane*16 implicit)
static __device__ __forceinline__ void gload16(const void* gsrc, void* ldst) {
    __builtin_amdgcn_global_load_lds(
        (const __attribute__((address_space(1))) unsigned int*)gsrc,
        (__attribute__((address_space(3))) unsigned int*)ldst,
        16, 0, 0);
}

// ---------------------------------------------------------------------------
// Kernel 1: V = X@W^T + b stored FRAGMENT-MAJOR as bf16:
//   Vf[((kb*8 + t)*64 + lane)*8 + e] = V[j][d],
//   j = kb*32 + (lane>>4)*8 + e, d = t*16 + (lane&15).
// A wave's B-fragment for (kb,t) is ONE contiguous 1KB load. (verified R5)
// ---------------------------------------------------------------------------
__global__ __launch_bounds__(256) void build_vf_kernel(
    const float* __restrict__ X, const float* __restrict__ W,
    const float* __restrict__ bias, short* __restrict__ Vf) {
    __shared__ float xs[32][128];
    const int jt = blockIdx.x * 32;
    for (int e = threadIdx.x; e < 32 * 128; e += 256) {
        xs[e >> 7][e & 127] = X[(size_t)(jt + (e >> 7)) * DIM + (e & 127)];
    }
    __syncthreads();
    const int d  = threadIdx.x & 127;
    const int jh = threadIdx.x >> 7;
    float bv = bias[d];
    float acc[16];
#pragma unroll
    for (int i = 0; i < 16; i++) acc[i] = bv;
    const float* wrow = W + (size_t)d * DIM;
    for (int k = 0; k < DIM; k += 4) {
        f32x4 wv = *(const f32x4*)(wrow + k);
#pragma unroll
        for (int i = 0; i < 16; i++) {
            f32x4 xv = *(const f32x4*)(&xs[jh * 16 + i][k]);
            acc[i] = fmaf(xv[0], wv[0], acc[i]);
            acc[i] = fmaf(xv[1], wv[1], acc[i]);
            acc[i] = fmaf(xv[2], wv[2], acc[i]);
            acc[i] = fmaf(xv[3], wv[3], acc[i]);
        }
    }
    bf16x8 o0, o1;
#pragma unroll
    for (int i = 0; i < 8; i++) { o0[i] = f2bf(acc[i]); o1[i] = f2bf(acc[8 + i]); }
    const int kb = jt >> 5;
    const int t  = d >> 4;
    short* base = Vf + ((size_t)(kb * 8 + t) * 64 + (d & 15) + 32 * jh) * 8;
    *(bf16x8*)(base)       = o0;   // kg = 2*jh
    *(bf16x8*)(base + 128) = o1;   // kg = 2*jh+1
}

// ---------------------------------------------------------------------------
// Kernel 2: fused masked-softmax(A) @ V.
//   Block: 256 thr (4 waves), tile 128 rows x 128 cols, K-chunk = kchunk.
//   Wave (wr,wc) owns 64x64: acc[4 rowgroups][4 t] f32x4.
//   Per KSTEP=64: stage A[128][64] f32 (32KB, dbuf, swizzled source->linear
//   LDS->swizzled ds_read_b128); B-frags direct from L2-resident Vf (1KB
//   contiguous loads, each reused over 4 rowgroups). One barrier per step.
// ---------------------------------------------------------------------------
template <int WRITE_PARTIAL>
__global__ __launch_bounds__(256, 2) void fused_kernel(
    const float* __restrict__ A, const short* __restrict__ Vf,
    float* __restrict__ dst, float* __restrict__ Zp, int kchunk) {

    __shared__ __align__(16) float abuf[16384];   // 2 x 32 KB A tiles
    __shared__ float zs[2][64];

    const int tid   = threadIdx.x;
    const int wid   = tid >> 6;
    const int lane  = tid & 63;
    const int row_a = lane & 15;
    const int kg    = lane >> 4;
    const int wr    = wid & 1;           // row half (64 rows)
    const int wc    = wid >> 1;          // col half (64 cols)
    const int rb    = blockIdx.x & (RB - 1);
    const int chunk = blockIdx.x >> 6;   // RB == 64
    const int r0    = rb * 128;
    const int k0    = chunk * kchunk;
    const int nsteps = kchunk >> 6;

    f32x4 acc[4][4];
#pragma unroll
    for (int rg = 0; rg < 4; rg++)
#pragma unroll
        for (int t = 0; t < 4; t++) acc[rg][t] = (f32x4)0.0f;
    float zacc[4] = {0.0f, 0.0f, 0.0f, 0.0f};

    // ---- staging helper data (recomputed per step to save VGPRs) ----
    const int sub   = lane >> 4;               // 0..3 row within 4-row gload
    const int schnk = lane & 15;               // 16B chunk within 64-float row

    // prologue: stage step 0 into buf half 0
#pragma unroll
    for (int i = 0; i < 8; i++) {
        const int row_s = wid * 32 + i * 4 + sub;
        gload16(A + (size_t)(r0 + row_s) * N_NODES + k0 + ((schnk ^ (row_s & 15)) << 2),
                abuf + (wid * 32 + i * 4) * 64);
    }

    for (int ks = 0; ks < nsteps; ks++) {
        __syncthreads();                       // stage(ks) visible; buf[ks-1] reads done
        if (ks + 1 < nsteps) {
            float* nb = abuf + ((ks + 1) & 1) * 8192;
#pragma unroll
            for (int i = 0; i < 8; i++) {
                const int row_s = wid * 32 + i * 4 + sub;
                gload16(A + (size_t)(r0 + row_s) * N_NODES + k0 + (ks + 1) * KSTEP
                          + ((schnk ^ (row_s & 15)) << 2),
                        nb + (wid * 32 + i * 4) * 64);
            }
        }
        const float* ab = abuf + (ks & 1) * 8192;
        const int kb_glob = (k0 >> 5) + ks * 2;
#pragma unroll
        for (int kb = 0; kb < 2; kb++) {
            // B-fragments for this kb: 4 contiguous 1KB loads (L2-hit)
            bf16x8 bv[4];
#pragma unroll
            for (int t = 0; t < 4; t++)
                bv[t] = *(const bf16x8*)(Vf + ((size_t)(kb_glob + kb) * 8 + wc * 4 + t) * 512 + lane * 8);
#pragma unroll
            for (int rg = 0; rg < 4; rg++) {
                const int row  = wr * 64 + rg * 16 + row_a;
                const int base = row * 64;
                const int c0   = kb * 8 + kg * 2;
                const f32x4 av0 = *(const f32x4*)(ab + base + (((c0 + 0) ^ row_a) << 2));
                const f32x4 av1 = *(const f32x4*)(ab + base + (((c0 + 1) ^ row_a) << 2));
                float p[8];
#pragma unroll
                for (int i = 0; i < 4; i++) {
                    p[i]     = (av0[i] > MASK_THRESH) ? __expf(av0[i]) : 0.0f;
                    p[i + 4] = (av1[i] > MASK_THRESH) ? __expf(av1[i]) : 0.0f;
                }
                bf16x8 af;
#pragma unroll
                for (int i = 0; i < 8; i++) { zacc[rg] += p[i]; af[i] = f2bf(p[i]); }
#pragma unroll
                for (int t = 0; t < 4; t++)
                    acc[rg][t] = __builtin_amdgcn_mfma_f32_16x16x32_bf16(af, bv[t], acc[rg][t], 0, 0, 0);
            }
        }
    }

    // ---- Z: fold the 4 kg groups per rowgroup; lanes 0..15 hold rows ----
#pragma unroll
    for (int rg = 0; rg < 4; rg++) {
        zacc[rg] += __shfl_xor(zacc[rg], 16);
        zacc[rg] += __shfl_xor(zacc[rg], 32);
    }
    if (wc == 0 && lane < 16) {
#pragma unroll
        for (int rg = 0; rg < 4; rg++) zs[wr][rg * 16 + lane] = zacc[rg];
    }
    __syncthreads();

    // ---- epilogue: each (row,col) owned by exactly one wave ----
    if (WRITE_PARTIAL) {
        float* nd = dst + (size_t)chunk * N_NODES * DIM;
#pragma unroll
        for (int rg = 0; rg < 4; rg++)
#pragma unroll
            for (int t = 0; t < 4; t++)
#pragma unroll
                for (int r = 0; r < 4; r++) {
                    const int row = r0 + wr * 64 + rg * 16 + kg * 4 + r;
                    const int col = wc * 64 + t * 16 + row_a;
                    nd[(size_t)row * DIM + col] = acc[rg][t][r];
                }
        if (wc == 0 && lane < 16) {
#pragma unroll
            for (int rg = 0; rg < 4; rg++)
                Zp[(size_t)chunk * N_NODES + r0 + wr * 64 + rg * 16 + lane] = zacc[rg];
        }
    } else {
#pragma unroll
        for (int rg = 0; rg < 4; rg++)
#pragma unroll
            for (int t = 0; t < 4; t++)
#pragma unroll
                for (int r = 0; r < 4; r++) {
                    const int row = r0 + wr * 64 + rg * 16 + kg * 4 + r;
                    const int col = wc * 64 + t * 16 + row_a;
                    const float v = acc[rg][t][r] / zs[wr][rg * 16 + kg * 4 + r];
                    dst[(size_t)row * DIM + col] = (v > 0.0f) ? v : 0.01f * v;
                }
    }
}

// ---------------------------------------------------------------------------
// Kernel 3: sum S partials, normalize, leaky_relu. float4 per thread.
// ---------------------------------------------------------------------------
__global__ __launch_bounds__(256) void reduce_kernel(
    const float* __restrict__ num, const float* __restrict__ Zp,
    float* __restrict__ out, int S) {
    const size_t i4 = (size_t)blockIdx.x * 256 + threadIdx.x;  // quad index
    const int r  = (int)(i4 >> 5);
    const int c4 = (int)(i4 & 31) * 4;
    f32x4 s = (f32x4)0.0f;
    float z = 0.0f;
    for (int p = 0; p < S; p++) {
        s += *(const f32x4*)(num + ((size_t)p * N_NODES + r) * DIM + c4);
        z += Zp[(size_t)p * N_NODES + r];
    }
    f32x4 o;
#pragma unroll
    for (int j = 0; j < 4; j++) {
        const float v = s[j] / z;
        o[j] = (v > 0.0f) ? v : 0.01f * v;
    }
    *(f32x4*)(out + (size_t)r * DIM + c4) = o;
}

extern "C" void kernel_launch(void* const* d_in, const int* in_sizes, int n_in,
                              void* d_out, int out_size, void* d_ws, size_t ws_size,
                              hipStream_t stream) {
    const float* A = (const float*)d_in[0];
    const float* X = (const float*)d_in[1];
    const float* W = (const float*)d_in[2];
    const float* b = (const float*)d_in[3];
    float* out = (float*)d_out;

    const size_t VF_BYTES = (size_t)DIM * N_NODES * 2;   // 2 MiB
    short* Vf = (short*)d_ws;
    build_vf_kernel<<<N_NODES / 32, 256, 0, stream>>>(X, W, b, Vf);

    const size_t per_split = ((size_t)N_NODES * DIM + N_NODES) * sizeof(float);
    int S = 1;
    for (int cand = 8; cand >= 1; cand >>= 1) {
        if (VF_BYTES + (size_t)cand * per_split <= ws_size) { S = cand; break; }
    }

    if (S >= 2) {
        float* num = (float*)((char*)d_ws + VF_BYTES);
        float* Zp  = num + (size_t)S * N_NODES * DIM;
        fused_kernel<1><<<RB * S, 256, 0, stream>>>(A, Vf, num, Zp, N_NODES / S);
        reduce_kernel<<<(N_NODES * DIM / 4) / 256, 256, 0, stream>>>(num, Zp, out, S);
    } else {
        fused_kernel<0><<<RB, 256, 0, stream>>>(A, Vf, out, nullptr, N_NODES);
    }
}